// Round 11
// baseline (286.681 us; speedup 1.0000x reference)
//
#include <hip/hip_runtime.h>
#include <math.h>

// ---------------------------------------------------------------------------
// VisionEncoderMambaBlock  (B=4, L=4096, D=256, d_state=16, T=1024)
// Round 26 = R25 kernels UNCHANGED + INSTRUMENTATION launch sequence:
//  - prep, gemm1, gemm2, scan1, scan2 are idempotent (pure stores) and are
//    launched TWICE each; scan3 (atomicAdd accumulator) once. Output is
//    bit-identical; the dur_us delta vs R25 (207.2us) measures
//    prep+gemm1+gemm2+scan1+scan2 directly, isolating scan3 and any
//    launch-overhead residual. Doubled kernels may also cross the top-5
//    display threshold, yielding per-kernel counters at last.
// ---------------------------------------------------------------------------

namespace {
constexpr int BB = 4;
constexpr int LL = 4096;
constexpr int DD = 256;
constexpr int NS = 16;       // d_state
constexpr int NCH = 128;
constexpr int CLEN = 32;     // LL / NCH
constexpr int NG  = CLEN / 8;
constexpr int TOK = 1024;

constexpr size_t NROW = (size_t)BB * LL;   // 16384
constexpr size_t NE   = NROW * DD;         // 4,194,304
constexpr size_t NP   = (size_t)BB * TOK * DD; // 1,048,576
constexpr size_t NBC  = NROW * NS;         // 262,144
constexpr size_t NAGG = 2ull * BB * DD * NCH * NS; // 8,388,608
constexpr size_t NSD  = 2ull * BB * NCH * DD;      // 262,144

constexpr size_t O_H1X  = 0;
constexpr size_t O_G2X  = NE / 2;
constexpr size_t O_H1T  = NE;                   // h1 tiled [rowgrp][d][8]
constexpr size_t O_G2T  = NE + NE / 2;
constexpr size_t O_DLTF = 2 * NE;               // delta_f tiled
constexpr size_t O_XN   = O_DLTF;               // xn bf16 aliases
constexpr size_t O_DLTB = 2 * NE + NE / 2;
constexpr size_t O_BMF  = 3 * NE;               // f32 NBC
constexpr size_t O_CMF  = O_BMF + NBC;
constexpr size_t O_BMB  = O_CMF + NBC;
constexpr size_t O_CMB  = O_BMB + NBC;
constexpr size_t O_ZP   = O_CMB + NBC;          // zp f32 (B,TOK,D)
constexpr size_t O_WF1  = O_ZP + NP;            // 768x256 bf16
constexpr size_t O_BF1  = O_WF1 + 768 * 256 / 2;
constexpr size_t O_WF2F = O_BF1 + 768;          // 384x256 bf16
constexpr size_t O_B2F  = O_WF2F + 384 * 256 / 2;
constexpr size_t O_WF2B = O_B2F + 384;
constexpr size_t O_B2B  = O_WF2B + 384 * 256 / 2;
constexpr size_t O_SD   = O_B2B + 384;          // f32 NSD
constexpr size_t O_HEND = O_SD + NSD;           // bf16 NAGG
constexpr size_t O_HIN  = O_HEND + NAGG / 2;    // bf16 NAGG
constexpr size_t O_MASK = O_HIN + NAGG / 2;     // 1024

constexpr int SST = 136;  // transposed stage col stride (bf16; 16B-aligned)
constexpr int NWPREP = 1282;  // weight-prep blocks (launched first)
} // namespace

typedef __bf16 bf16x8 __attribute__((ext_vector_type(8)));
typedef __bf16 bf16x4 __attribute__((ext_vector_type(4)));
typedef float f32x4 __attribute__((ext_vector_type(4)));

__device__ __forceinline__ float softplusf(float x) {
    return fmaxf(x, 0.f) + __logf(1.f + __expf(-fabsf(x)));
}
__device__ __forceinline__ float siluf(float x) {
    return x / (1.f + __expf(-x));
}
__device__ __forceinline__ void gl_lds16(const void* g, void* l) {
    __builtin_amdgcn_global_load_lds((const __attribute__((address_space(1))) unsigned int*)g,
                                     (__attribute__((address_space(3))) unsigned int*)l, 16, 0, 0);
}
__device__ __forceinline__ int st_addr(int col, int row) {
    return col * SST + ((((row >> 3) ^ (col >> 3)) & 15) << 3) + (row & 7);
}
// p[n] = e1^(n+1), log-depth-4 chain (15 muls)
__device__ __forceinline__ void pow_chain(float e1, float* p) {
    p[0] = e1;
    p[1] = e1 * e1;
    p[2] = p[1] * e1;
    p[3] = p[1] * p[1];
    p[4] = p[3] * p[0];
    p[5] = p[3] * p[1];
    p[6] = p[3] * p[2];
    p[7] = p[3] * p[3];
    p[8]  = p[7] * p[0];
    p[9]  = p[7] * p[1];
    p[10] = p[7] * p[2];
    p[11] = p[7] * p[3];
    p[12] = p[7] * p[4];
    p[13] = p[7] * p[5];
    p[14] = p[7] * p[6];
    p[15] = p[7] * p[7];
}

// ---------------------------------------------------------------------------
// Pipelined BK=32 K-loop shared by both GEMMs (R17 form + T5 setprio).
// ---------------------------------------------------------------------------
#define GEMM_KLOOP(SHBASE, GA, GB, WR, WC, WV, LANE, ACC)                          \
    {                                                                               \
        _Pragma("unroll")                                                           \
        for (int rg = 0; rg < 2; ++rg) {                                            \
            gl_lds16((GA) + rg * 16 * 256, &(SHBASE)[((WV) * 2 + rg) * 512]);       \
            gl_lds16((GB) + rg * 16 * 256, &(SHBASE)[4096 + ((WV) * 2 + rg) * 512]);\
        }                                                                           \
        _Pragma("unroll")                                                           \
        for (int kst = 0; kst < 8; ++kst) {                                         \
            if (kst < 7) {                                                          \
                __bf16* Asn = (SHBASE) + ((kst + 1) & 1) * 8192;                    \
                int k0n = (kst + 1) * 32;                                           \
                _Pragma("unroll")                                                   \
                for (int rg = 0; rg < 2; ++rg) {                                    \
                    gl_lds16((GA) + rg * 16 * 256 + k0n, &Asn[((WV) * 2 + rg) * 512]);      \
                    gl_lds16((GB) + rg * 16 * 256 + k0n, &Asn[4096 + ((WV) * 2 + rg) * 512]);\
                }                                                                   \
                asm volatile("s_waitcnt vmcnt(4)" ::: "memory");                    \
            } else {                                                                \
                asm volatile("s_waitcnt vmcnt(0)" ::: "memory");                    \
            }                                                                       \
            __builtin_amdgcn_s_barrier();                                           \
            __builtin_amdgcn_sched_barrier(0);                                      \
            const __bf16* Ac = (SHBASE) + (kst & 1) * 8192;                         \
            const __bf16* Bc = Ac + 4096;                                           \
            bf16x8 af[4], bfr[4];                                                   \
            _Pragma("unroll")                                                       \
            for (int i = 0; i < 4; ++i)                                             \
                af[i] = *(const bf16x8*)&Ac[((WR) * 4 + i) * 512 + (LANE) * 8];     \
            _Pragma("unroll")                                                       \
            for (int j = 0; j < 4; ++j)                                             \
                bfr[j] = *(const bf16x8*)&Bc[((WC) * 4 + j) * 512 + (LANE) * 8];    \
            __builtin_amdgcn_s_setprio(1);                                          \
            _Pragma("unroll")                                                       \
            for (int i = 0; i < 4; ++i)                                             \
                _Pragma("unroll")                                                   \
                for (int j = 0; j < 4; ++j)                                         \
                    ACC[i][j] = __builtin_amdgcn_mfma_f32_16x16x32_bf16(af[i], bfr[j], ACC[i][j], 0, 0, 0); \
            __builtin_amdgcn_s_setprio(0);                                          \
            __builtin_amdgcn_s_barrier();                                           \
        }                                                                           \
    }

// ---------------------------------------------------------------------------
// Fused prep + LN (R22 form): weight prep FIRST, LN wave-per-row after.
// ---------------------------------------------------------------------------
__global__ __launch_bounds__(256) void prep_ln_kernel(
    const float* __restrict__ x, const float* __restrict__ lng, const float* __restrict__ lnb,
    const float* __restrict__ W1, const float* __restrict__ b1,
    const float* __restrict__ W2, const float* __restrict__ b2,
    const float* __restrict__ Wcf, const float* __restrict__ bcf,
    const float* __restrict__ Wcb, const float* __restrict__ bcb,
    const float* __restrict__ Wdt_f, const float* __restrict__ Wdbc_f, const float* __restrict__ bdt_f,
    const float* __restrict__ Wdt_b, const float* __restrict__ Wdbc_b, const float* __restrict__ bdt_b,
    __bf16* __restrict__ xn, float* __restrict__ outp,
    __bf16* __restrict__ Wf1, float* __restrict__ bf1,
    __bf16* __restrict__ Wf2f, float* __restrict__ b2f,
    __bf16* __restrict__ Wf2b, float* __restrict__ b2b,
    float* __restrict__ mask)
{
    int bxg = blockIdx.x;
    int k = threadIdx.x;
    if (bxg >= NWPREP) {
        // ---- LN: 4 waves, wave w owns row r0+w ----
        __shared__ float ls[4][256];   // raw rows for skip-pool
        int r0 = (bxg - NWPREP) * 4;
        int w = k >> 6, l = k & 63;
        int row = r0 + w;
        float4 v = *(const float4*)&x[(size_t)row * 256 + l * 4];
        float s = v.x + v.y + v.z + v.w;
        float q = v.x * v.x + v.y * v.y + v.z * v.z + v.w * v.w;
        for (int o = 32; o > 0; o >>= 1) {
            s += __shfl_xor(s, o, 64);
            q += __shfl_xor(q, o, 64);
        }
        float mu = s * (1.f / 256.f);
        float rs = rsqrtf(q * (1.f / 256.f) - mu * mu + 1e-5f);
        float4 g4 = *(const float4*)&lng[l * 4];
        float4 b4 = *(const float4*)&lnb[l * 4];
        bf16x4 o4;
        o4[0] = (__bf16)((v.x - mu) * rs * g4.x + b4.x);
        o4[1] = (__bf16)((v.y - mu) * rs * g4.y + b4.y);
        o4[2] = (__bf16)((v.z - mu) * rs * g4.z + b4.z);
        o4[3] = (__bf16)((v.w - mu) * rs * g4.w + b4.w);
        *(bf16x4*)&xn[(size_t)row * 256 + l * 4] = o4;
        *(float4*)&ls[w][l * 4] = v;
        __syncthreads();
        int b = r0 >> 12;
        int g = (r0 & 4095) >> 2;
        float acc = ls[0][k] + ls[1][k] + ls[2][k] + ls[3][k];
        outp[((size_t)b * TOK + g) * 256 + k] = acc * 0.25f;   // skip -> out init
        return;
    }
    int j2 = bxg;                 // 0..1281
    int mat = j2 / 641;
    int bx = j2 % 641;
    if (bx < 256) {
        int j = bx;
        const float* Wc = mat ? Wcb : Wcf;
        float acc = 0.f, accb = 0.f;
#pragma unroll 8
        for (int m = 0; m < 256; ++m) {
            float w = Wc[j * 256 + m];
            acc  = fmaf(w, W2[m * 256 + k], acc);
            accb = fmaf(w, b2[m], accb);
        }
        Wf1[(size_t)(256 + mat * 256 + j) * 256 + k] = (__bf16)acc;
        if (k == 0) bf1[256 + mat * 256 + j] = accb + (mat ? bcb[j] : bcf[j]);
        if (mat == 0) {
            Wf1[(size_t)j * 256 + k] = (__bf16)W1[j * 256 + k];
            if (k == 0) bf1[j] = b1[j];
        }
    } else if (bx < 640) {
        int j = bx - 256;
        const float* Wdt  = mat ? Wdt_b : Wdt_f;
        const float* Wdbc = mat ? Wdbc_b : Wdbc_f;
        const float* bdt  = mat ? bdt_b : bdt_f;
        __bf16* Wf2 = mat ? Wf2b : Wf2f;
        float* b2x  = mat ? b2b : b2f;
        float val;
        if (j < 256) {
            float acc = 0.f;
#pragma unroll
            for (int m = 0; m < 16; ++m)
                acc = fmaf(Wdt[j * 16 + m], Wdbc[m * 256 + k], acc);
            val = acc;
        } else if (j < 288) {
            val = Wdbc[(16 + (j - 256)) * 256 + k];
        } else {
            val = 0.f;
        }
        Wf2[(size_t)j * 256 + k] = (__bf16)val;
        if (k == 0) b2x[j] = (j < 256) ? bdt[j] : 0.f;
    } else if (mat == 0) {
        __shared__ float red2[4];
        __shared__ float sb;
        float w[4];
        float loc = 0.f;
#pragma unroll
        for (int q = 0; q < 4; ++q) {
            float dd = (float)(k + 256 * q) - 512.f;
            w[q] = __expf(-0.5f * dd * dd * (1.f / 65536.f));
            loc += w[q];
        }
        for (int o = 32; o > 0; o >>= 1) loc += __shfl_xor(loc, o, 64);
        if ((k & 63) == 0) red2[k >> 6] = loc;
        __syncthreads();
        if (k == 0) sb = red2[0] + red2[1] + red2[2] + red2[3];
        __syncthreads();
        float inv = 1.f / sb;
#pragma unroll
        for (int q = 0; q < 4; ++q) mask[k + 256 * q] = w[q] * inv;
    }
}

// ---------------------------------------------------------------------------
// MFMA GEMM1 (unchanged from R22).
// ---------------------------------------------------------------------------
__global__ __launch_bounds__(256) void gemm1_mfma(
    const __bf16* __restrict__ A, const __bf16* __restrict__ Bw, const float* __restrict__ bias,
    float* __restrict__ zp, __bf16* __restrict__ h1x, __bf16* __restrict__ g2x,
    __bf16* __restrict__ h1T, __bf16* __restrict__ g2T)
{
    __shared__ __align__(16) __bf16 SH[128 * SST];   // 34816B; K-loop uses 32KB
    int tid = threadIdx.x;
    int lane = tid & 63, wv = tid >> 6;
    int wr = wv >> 1, wc = wv & 1;
    int lm = lane & 15, lq = lane >> 4;
    int m0 = blockIdx.x << 7, n0 = blockIdx.y << 7;

    const __bf16* gaB = A  + (size_t)(m0 + wv * 32 + lm) * 256 + lq * 8;
    const __bf16* gbB = Bw + (size_t)(n0 + wv * 32 + lm) * 256 + lq * 8;

    f32x4 acc[4][4];
#pragma unroll
    for (int i = 0; i < 4; ++i)
#pragma unroll
        for (int j = 0; j < 4; ++j) acc[i][j] = 0;

    GEMM_KLOOP(SH, gaB, gbB, wr, wc, wv, lane, acc)

    int target = blockIdx.y >> 1;  // 0:z 1:h1 2:g2
    int colbase = (blockIdx.y & 1) * 128;
    __syncthreads();
    if (target == 0) {
        float* zs = (float*)SH;
#pragma unroll
        for (int j = 0; j < 4; ++j) {
            int coll = wc * 64 + j * 16 + lm;
            float bv = bias[n0 + coll];
#pragma unroll
            for (int i = 0; i < 4; ++i) {
                int gl = wr * 16 + i * 4 + lq;
                float s = acc[i][j][0] + acc[i][j][1] + acc[i][j][2] + acc[i][j][3];
                zs[gl * 132 + coll] = siluf(0.25f * s + bv);
            }
        }
        __syncthreads();
        int b = m0 >> 12, g0 = (m0 & 4095) >> 2;
        int rl = tid >> 5;
        int c4 = (tid & 31) * 4;
#pragma unroll
        for (int p = 0; p < 4; ++p) {
            int g = p * 8 + rl;
            float4 v = *(float4*)&zs[g * 132 + c4];
            *(float4*)&zp[((size_t)b * TOK + g0 + g) * 256 + colbase + c4] = v;
        }
    } else {
        __bf16* hs = SH;
#pragma unroll
        for (int j = 0; j < 4; ++j) {
            int coll = wc * 64 + j * 16 + lm;
            float bv = bias[n0 + coll];
#pragma unroll
            for (int i = 0; i < 4; ++i) {
                int rl = wr * 64 + i * 16 + lq * 4;
                bf16x4 v4;
#pragma unroll
                for (int r = 0; r < 4; ++r)
                    v4[r] = (__bf16)softplusf(acc[i][j][r] + bv);
                *(bf16x4*)&hs[st_addr(coll, rl)] = v4;
            }
        }
        __syncthreads();
        __bf16* outp = (target == 1) ? h1x : g2x;
        __bf16* outT = (target == 1) ? h1T : g2T;
        {
            int tg = tid >> 4;
#pragma unroll
            for (int it = 0; it < 8; ++it) {
                int dcol = it * 16 + (tid & 15);
                bf16x8 v = *(const bf16x8*)&hs[dcol * SST + (((tg ^ (dcol >> 3)) & 15) << 3)];
                *(bf16x8*)&outT[(((size_t)(m0 >> 3) + tg) * 256 + colbase + dcol) * 8] = v;
            }
        }
        {
            int rl2 = tid >> 4;
            int c8 = (tid & 15) * 8;
#pragma unroll
            for (int p = 0; p < 8; ++p) {
                int row = p * 16 + rl2;
                bf16x8 v;
#pragma unroll
                for (int e = 0; e < 8; ++e) v[e] = hs[st_addr(c8 + e, row)];
                *(bf16x8*)&outp[(size_t)(m0 + row) * 256 + colbase + c8] = v;
            }
        }
    }
}

// ---------------------------------------------------------------------------
// MFMA GEMM2 (per dir): y<2 delta (unchanged); y==2 Bm/Cm epilogue f32.
// ---------------------------------------------------------------------------
__global__ __launch_bounds__(256) void gemm2_mfma(
    const __bf16* __restrict__ h1x, const __bf16* __restrict__ g2x,
    const __bf16* __restrict__ Wf, const float* __restrict__ bf2,
    const __bf16* __restrict__ Wb, const float* __restrict__ bb2,
    __bf16* __restrict__ dTf, __bf16* __restrict__ dTb,
    float* __restrict__ BmF, float* __restrict__ CmF,
    float* __restrict__ BmB, float* __restrict__ CmB)
{
    __shared__ __align__(16) __bf16 SH[128 * SST];
    int tid = threadIdx.x;
    int lane = tid & 63, wv = tid >> 6;
    int wr = wv >> 1, wc = wv & 1;
    int lm = lane & 15, lq = lane >> 4;
    int m0 = blockIdx.x << 7, n0 = blockIdx.y << 7;
    int dir = blockIdx.z;
    const __bf16* A    = dir ? g2x : h1x;
    const __bf16* Bw   = dir ? Wb : Wf;
    const float* bias  = dir ? bb2 : bf2;
    __bf16* dT = dir ? dTb : dTf;
    float* Bm = dir ? BmB : BmF;
    float* Cm = dir ? CmB : CmF;

    const __bf16* gaB = A  + (size_t)(m0 + wv * 32 + lm) * 256 + lq * 8;
    const __bf16* gbB = Bw + (size_t)(n0 + wv * 32 + lm) * 256 + lq * 8;

    f32x4 acc[4][4];
#pragma unroll
    for (int i = 0; i < 4; ++i)
#pragma unroll
        for (int j = 0; j < 4; ++j) acc[i][j] = 0;

    GEMM_KLOOP(SH, gaB, gbB, wr, wc, wv, lane, acc)

    __syncthreads();
    if (blockIdx.y < 2) {
        __bf16* hs = SH;
        int colbase = blockIdx.y * 128;
#pragma unroll
        for (int j = 0; j < 4; ++j) {
            int coll = wc * 64 + j * 16 + lm;
            float bv = bias[n0 + coll];
#pragma unroll
            for (int i = 0; i < 4; ++i) {
                int rl = wr * 64 + i * 16 + lq * 4;
                bf16x4 v4;
#pragma unroll
                for (int r = 0; r < 4; ++r)
                    v4[r] = (__bf16)softplusf(acc[i][j][r] + bv);
                *(bf16x4*)&hs[st_addr(coll, rl)] = v4;
            }
        }
        __syncthreads();
        int tg = tid >> 4;
#pragma unroll
        for (int it = 0; it < 8; ++it) {
            int dcol = it * 16 + (tid & 15);
            bf16x8 v = *(const bf16x8*)&hs[dcol * SST + (((tg ^ (dcol >> 3)) & 15) << 3)];
            *(bf16x8*)&dT[(((size_t)(m0 >> 3) + tg) * 256 + colbase + dcol) * 8] = v;
        }
    } else {
        float* bs_ = (float*)SH;            // 128 x 24 f32 (12KB)
        float* cs_ = (float*)SH + 128 * 24; // 128 x 24 f32 (12KB)
        if (wc == 0) {
#pragma unroll
            for (int j = 0; j < 2; ++j) {
                int coll = j * 16 + lm;
                float bv = bias[n0 + coll];
                float* dst = j ? cs_ : bs_;
#pragma unroll
                for (int i = 0; i < 4; ++i) {
                    int rl = wr * 64 + i * 16 + lq * 4;
#pragma unroll
                    for (int r = 0; r < 4; ++r)
                        dst[(rl + r) * 24 + lm] = acc[i][j][r] + bv;
                }
            }
        }
        __syncthreads();
        int row = tid >> 1;
        int h8 = (tid & 1) * 8;
        float4 vb0 = *(float4*)&bs_[row * 24 + h8];
        float4 vb1 = *(float4*)&bs_[row * 24 + h8 + 4];
        float4 vc0 = *(float4*)&cs_[row * 24 + h8];
        float4 vc1 = *(float4*)&cs_[row * 24 + h8 + 4];
        *(float4*)&Bm[(size_t)(m0 + row) * 16 + h8]     = vb0;
        *(float4*)&Bm[(size_t)(m0 + row) * 16 + h8 + 4] = vb1;
        *(float4*)&Cm[(size_t)(m0 + row) * 16 + h8]     = vc0;
        *(float4*)&Cm[(size_t)(m0 + row) * 16 + h8 + 4] = vc1;
    }
}

// ---------------------------------------------------------------------------
// Scan pass 1: f32 Bm; rolled R11 loop.
// ---------------------------------------------------------------------------
__global__ __launch_bounds__(256) void scan1_kernel(
    const __bf16* __restrict__ dTf, const __bf16* __restrict__ dTb,
    const __bf16* __restrict__ xTf, const __bf16* __restrict__ xTb,
    const float* __restrict__ bmf, const float* __restrict__ bmb,
    const float* __restrict__ alogf, const float* __restrict__ alogb,
    float* __restrict__ sdb, __bf16* __restrict__ hend)
{
    int d = threadIdx.x;
    int c = blockIdx.x, b = blockIdx.y, dir = blockIdx.z;
    const __bf16* dT = dir ? dTb : dTf;
    const __bf16* xT = dir ? xTb : xTf;
    const float* Bm = dir ? bmb : bmf;
    const float* Alog = dir ? alogb : alogf;

    float A[16];
    bool intOK = true;
#pragma unroll
    for (int n = 0; n < 16; ++n) {
        A[n] = -__expf(Alog[(size_t)d * 16 + n]);
        intOK = intOK && (fabsf(A[n] + (float)(n + 1)) < 1e-3f);
    }
    float h[16];
#pragma unroll
    for (int n = 0; n < 16; ++n) h[n] = 0.f;
    float sd = 0.f;
    size_t rg0 = (size_t)b * 512 + (size_t)c * NG;
    size_t rowb = (size_t)b * LL + (size_t)c * CLEN;
    if (intOK) {
        for (int g = 0; g < NG; ++g) {
            int gg = dir ? (NG - 1 - g) : g;
            size_t ti = ((rg0 + gg) * 256 + d) * 8;
            bf16x8 dv = *(const bf16x8*)&dT[ti];
            bf16x8 xv8 = *(const bf16x8*)&xT[ti];
#pragma unroll
            for (int ii = 0; ii < 8; ++ii) {
                int i = dir ? (7 - ii) : ii;
                float dlt = (float)dv[i];
                float xv  = (float)xv8[i];
                float common = dlt * xv;
                sd += dlt;
                float p[16];
                pow_chain(__expf(-dlt), p);
                const f32x4* Bp = (const f32x4*)&Bm[(rowb + gg * 8 + i) * NS];
                f32x4 B0 = Bp[0], B1 = Bp[1], B2 = Bp[2], B3 = Bp[3];
#pragma unroll
                for (int n = 0; n < 4; ++n) {
                    h[n]      = fmaf(p[n],      h[n],      common * B0[n]);
                    h[n + 4]  = fmaf(p[n + 4],  h[n + 4],  common * B1[n]);
                    h[n + 8]  = fmaf(p[n + 8],  h[n + 8],  common * B2[n]);
                    h[n + 12] = fmaf(p[n + 12], h[n + 12], common * B3[n]);
                }
            }
        }
    } else {
        for (int g = 0; g < NG; ++g) {
            int gg = dir ? (NG - 1 - g) : g;
            size_t ti = ((rg0 + gg) * 256 + d) * 8;
            bf16x8 dv = *(const bf16x8*)&dT[ti];
            bf16x8 xv8 = *(const bf16x8*)&xT[ti];
#pragma unroll
            for (int ii = 0; ii < 8; ++ii) {
                int i = dir ? (7 - ii) : ii;
                float dlt = (float)dv[i];
                float xv  = (float)xv8[i];
                float common = dlt * xv;
                sd += dlt;
                const f32x4* Bp = (const f32x4*)&Bm[(rowb + gg * 8 + i) * NS];
                f32x4 B0 = Bp[0], B1 = Bp[1], B2 = Bp[2], B3 = Bp[3];
#pragma unroll
                for (int n = 0; n < 4; ++n) {
                    h[n]      = fmaf(__expf(dlt * A[n]),      h[n],      common * B0[n]);
                    h[n + 4]  = fmaf(__expf(dlt * A[n + 4]),  h[n + 4],  common * B1[n]);
                    h[n + 8]  = fmaf(__expf(dlt * A[n + 8]),  h[n + 8],  common * B2[n]);
                    h[n + 12] = fmaf(__expf(dlt * A[n + 12]), h[n + 12], common * B3[n]);
                }
            }
        }
    }
    size_t sbase = (size_t)(dir * 4 + b) * NCH + c;
    sdb[sbase * 256 + d] = sd;
    size_t hb = sbase * 16 * 256 + d;
#pragma unroll
    for (int n = 0; n < 16; ++n) hend[hb + (size_t)n * 256] = (__bf16)h[n];
}

// ---------------------------------------------------------------------------
// Scan pass 2 (unchanged): 256 blocks x 128 threads.
// ---------------------------------------------------------------------------
__global__ __launch_bounds__(128) void scan2_kernel(
    const float* __restrict__ sdb, const __bf16* __restrict__ hend,
    const float* __restrict__ alogf, const float* __restrict__ alogb,
    __bf16* __restrict__ hin)
{
    int blk = blockIdx.x >> 1;   // 0..127
    int n = blk & 15, b = (blk >> 4) & 3, dir = blk >> 6;
    int d = ((blockIdx.x & 1) << 7) + threadIdx.x;
    const float* Alog = dir ? alogb : alogf;
    float A_dn = -__expf(Alog[(size_t)d * 16 + n]);
    size_t basec = (size_t)(dir * 4 + b) * NCH;
    float s = 0.f;
    if (!dir) {
#pragma unroll 8
        for (int c = 0; c < NCH; ++c) {
            float sdv = sdb[(basec + c) * 256 + d];
            size_t idx = ((basec + c) * 16 + n) * 256 + d;
            float he = (float)hend[idx];
            hin[idx] = (__bf16)s;
            s = fmaf(__expf(sdv * A_dn), s, he);
        }
    } else {
#pragma unroll 8
        for (int c = NCH - 1; c >= 0; --c) {
            float sdv = sdb[(basec + c) * 256 + d];
            size_t idx = ((basec + c) * 16 + n) * 256 + d;
            float he = (float)hend[idx];
            hin[idx] = (__bf16)s;
            s = fmaf(__expf(sdv * A_dn), s, he);
        }
    }
}

// ---------------------------------------------------------------------------
// Scan pass 3: f32 Bm/Cm, 4-way yac; atomicAdd epilogue (NOT idempotent,
// launched once).
// ---------------------------------------------------------------------------
__global__ __launch_bounds__(256) void scan3_kernel(
    const __bf16* __restrict__ dTf, const __bf16* __restrict__ dTb,
    const __bf16* __restrict__ xTf, const __bf16* __restrict__ xTb,
    const float* __restrict__ bmf, const float* __restrict__ bmb,
    const float* __restrict__ cmf, const float* __restrict__ cmb,
    const float* __restrict__ alogf, const float* __restrict__ alogb,
    const float* __restrict__ Dfp, const float* __restrict__ Dbp,
    const __bf16* __restrict__ hin,
    const float* __restrict__ zp, const float* __restrict__ mask,
    float* __restrict__ outp)
{
    int d = threadIdx.x;
    int c = blockIdx.x, b = blockIdx.y, dir = blockIdx.z;
    const __bf16* dT = dir ? dTb : dTf;
    const __bf16* xT = dir ? xTb : xTf;
    const float* Bm = dir ? bmb : bmf;
    const float* Cm = dir ? cmb : cmf;
    const float* Alog = dir ? alogb : alogf;
    const float* Dv   = dir ? Dbp : Dfp;

    float A[16];
    bool intOK = true;
#pragma unroll
    for (int n = 0; n < 16; ++n) {
        A[n] = -__expf(Alog[(size_t)d * 16 + n]);
        intOK = intOK && (fabsf(A[n] + (float)(n + 1)) < 1e-3f);
    }
    float Dd = Dv[d];
    float h[16];
    size_t hb = ((size_t)(dir * 4 + b) * NCH + c) * 16 * 256 + d;
#pragma unroll
    for (int n = 0; n < 16; ++n) h[n] = (float)hin[hb + (size_t)n * 256];

    size_t rg0 = (size_t)b * 512 + (size_t)c * NG;
    size_t rowb = (size_t)b * LL + (size_t)c * CLEN;
    int base = c * CLEN;
    float pool = 0.f;
    if (intOK) {
        for (int g = 0; g < NG; ++g) {
            int gg = dir ? (NG - 1 - g) : g;
            size_t ti = ((rg0 + gg) * 256 + d) * 8;
            bf16x8 dv = *(const bf16x8*)&dT[ti];
            bf16x8 xv8 = *(const bf16x8*)&xT[ti];
#pragma unroll
            for (int ii = 0; ii < 8; ++ii) {
                int i = dir ? (7 - ii) : ii;
                float dlt = (float)dv[i];
                float xv  = (float)xv8[i];
                float common = dlt * xv;
                float p[16];
                pow_chain(__expf(-dlt), p);
                size_t row = rowb + gg * 8 + i;
                const f32x4* Bp = (const f32x4*)&Bm[row * NS];
                const f32x4* Cp = (const f32x4*)&Cm[row * NS];
                f32x4 B0 = Bp[0], B1 = Bp[1], B2 = Bp[2], B3 = Bp[3];
                f32x4 C0 = Cp[0], C1 = Cp[1], C2 = Cp[2], C3 = Cp[3];
                float y0 = 0.f, y1 = 0.f, y2 = 0.f, y3 = 0.f;
#pragma unroll
                for (int n = 0; n < 4; ++n) {
                    h[n]      = fmaf(p[n],      h[n],      common * B0[n]);
                    h[n + 4]  = fmaf(p[n + 4],  h[n + 4],  common * B1[n]);
                    h[n + 8]  = fmaf(p[n + 8],  h[n + 8],  common * B2[n]);
                    h[n + 12] = fmaf(p[n + 12], h[n + 12], common * B3[n]);
                    y0 = fmaf(h[n],      C0[n], y0);
                    y1 = fmaf(h[n + 4],  C1[n], y1);
                    y2 = fmaf(h[n + 8],  C2[n], y2);
                    y3 = fmaf(h[n + 12], C3[n], y3);
                }
                pool += (y0 + y1) + (y2 + y3) + Dd * xv;
                int t = base + gg * 8 + i;
                bool gend = dir ? ((t & 3) == 0) : ((t & 3) == 3);
                if (gend) {
                    int gtok = t >> 2;
                    size_t ip = ((size_t)b * TOK + gtok) * 256 + d;
                    float contrib = zp[ip] * siluf(pool * 0.25f * mask[gtok]);
                    atomicAdd(&outp[ip], contrib);
                    pool = 0.f;
                }
            }
        }
    } else {
        for (int g = 0; g < NG; ++g) {
            int gg = dir ? (NG - 1 - g) : g;
            size_t ti = ((rg0 + gg) * 256 + d) * 8;
            bf16x8 dv = *(const bf16x8*)&dT[ti];
            bf16x8 xv8 = *(const bf16x8*)&xT[ti];
#pragma unroll
            for (int ii = 0; ii < 8; ++ii) {
                int i = dir ? (7 - ii) : ii;
                float dlt = (float)dv[i];
                float xv  = (float)xv8[i];
                float common = dlt * xv;
                size_t row = rowb + gg * 8 + i;
                const f32x4* Bp = (const f32x4*)&Bm[row * NS];
                const f32x4* Cp = (const f32x4*)&Cm[row * NS];
                f32x4 B0 = Bp[0], B1 = Bp[1], B2 = Bp[2], B3 = Bp[3];
                f32x4 C0 = Cp[0], C1 = Cp[1], C2 = Cp[2], C3 = Cp[3];
                float y0 = 0.f, y1 = 0.f, y2 = 0.f, y3 = 0.f;
#pragma unroll
                for (int n = 0; n < 4; ++n) {
                    h[n]      = fmaf(__expf(dlt * A[n]),      h[n],      common * B0[n]);
                    h[n + 4]  = fmaf(__expf(dlt * A[n + 4]),  h[n + 4],  common * B1[n]);
                    h[n + 8]  = fmaf(__expf(dlt * A[n + 8]),  h[n + 8],  common * B2[n]);
                    h[n + 12] = fmaf(__expf(dlt * A[n + 12]), h[n + 12], common * B3[n]);
                    y0 = fmaf(h[n],      C0[n], y0);
                    y1 = fmaf(h[n + 4],  C1[n], y1);
                    y2 = fmaf(h[n + 8],  C2[n], y2);
                    y3 = fmaf(h[n + 12], C3[n], y3);
                }
                pool += (y0 + y1) + (y2 + y3) + Dd * xv;
                int t = base + gg * 8 + i;
                bool gend = dir ? ((t & 3) == 0) : ((t & 3) == 3);
                if (gend) {
                    int gtok = t >> 2;
                    size_t ip = ((size_t)b * TOK + gtok) * 256 + d;
                    float contrib = zp[ip] * siluf(pool * 0.25f * mask[gtok]);
                    atomicAdd(&outp[ip], contrib);
                    pool = 0.f;
                }
            }
        }
    }
}

// ---------------------------------------------------------------------------
extern "C" void kernel_launch(void* const* d_in, const int* in_sizes, int n_in,
                              void* d_out, int out_size, void* d_ws, size_t ws_size,
                              hipStream_t stream)
{
    const float* x      = (const float*)d_in[0];
    const float* ln_g   = (const float*)d_in[1];
    const float* ln_b   = (const float*)d_in[2];
    const float* W1     = (const float*)d_in[3];
    const float* b1     = (const float*)d_in[4];
    const float* W2     = (const float*)d_in[5];
    const float* b2     = (const float*)d_in[6];
    const float* Wcf    = (const float*)d_in[7];
    const float* bcf    = (const float*)d_in[8];
    const float* Wcb    = (const float*)d_in[9];
    const float* bcb    = (const float*)d_in[10];
    const float* Wdbc_f = (const float*)d_in[11];
    const float* Wdt_f  = (const float*)d_in[12];
    const float* bdt_f  = (const float*)d_in[13];
    const float* Alog_f = (const float*)d_in[14];
    const float* D_f    = (const float*)d_in[15];
    const float* Wdbc_b = (const float*)d_in[16];
    const float* Wdt_b  = (const float*)d_in[17];
    const float* bdt_b  = (const float*)d_in[18];
    const float* Alog_b = (const float*)d_in[19];
    const float* D_b    = (const float*)d_in[20];
    float* out = (float*)d_out;
    float* ws  = (float*)d_ws;

    __bf16* h1x = (__bf16*)(ws + O_H1X);
    __bf16* g2x = (__bf16*)(ws + O_G2X);
    __bf16* h1T = (__bf16*)(ws + O_H1T);
    __bf16* g2T = (__bf16*)(ws + O_G2T);
    __bf16* xnb = (__bf16*)(ws + O_XN);
    __bf16* dTf = (__bf16*)(ws + O_DLTF);
    __bf16* dTb = (__bf16*)(ws + O_DLTB);
    float* bmf = ws + O_BMF;
    float* cmf = ws + O_CMF;
    float* bmb = ws + O_BMB;
    float* cmb = ws + O_CMB;
    float* zpb  = ws + O_ZP;
    __bf16* wf1 = (__bf16*)(ws + O_WF1);
    float* bf1  = ws + O_BF1;
    __bf16* wf2f = (__bf16*)(ws + O_WF2F);
    float* b2f  = ws + O_B2F;
    __bf16* wf2b = (__bf16*)(ws + O_WF2B);
    float* b2b  = ws + O_B2B;
    float* sdb  = ws + O_SD;
    __bf16* hnd = (__bf16*)(ws + O_HEND);
    __bf16* hin = (__bf16*)(ws + O_HIN);
    float* mkb  = ws + O_MASK;

    // --- instrumentation: idempotent kernels launched twice ---
    for (int rep = 0; rep < 2; ++rep)
        prep_ln_kernel<<<dim3(4096 + NWPREP), 256, 0, stream>>>(
            x, ln_g, ln_b,
            W1, b1, W2, b2, Wcf, bcf, Wcb, bcb,
            Wdt_f, Wdbc_f, bdt_f, Wdt_b, Wdbc_b, bdt_b,
            xnb, out, wf1, bf1, wf2f, b2f, wf2b, b2b, mkb);
    for (int rep = 0; rep < 2; ++rep)
        gemm1_mfma<<<dim3(128, 6), 256, 0, stream>>>(xnb, wf1, bf1, zpb, h1x, g2x, h1T, g2T);
    for (int rep = 0; rep < 2; ++rep)
        gemm2_mfma<<<dim3(128, 3, 2), 256, 0, stream>>>(h1x, g2x, wf2f, b2f, wf2b, b2b,
                                                        dTf, dTb, bmf, cmf, bmb, cmb);
    for (int rep = 0; rep < 2; ++rep)
        scan1_kernel<<<dim3(NCH, BB, 2), 256, 0, stream>>>(dTf, dTb, h1T, g2T, bmf, bmb,
                                                           Alog_f, Alog_b, sdb, hnd);
    for (int rep = 0; rep < 2; ++rep)
        scan2_kernel<<<256, 128, 0, stream>>>(sdb, hnd, Alog_f, Alog_b, hin);
    scan3_kernel<<<dim3(NCH, BB, 2), 256, 0, stream>>>(dTf, dTb, h1T, g2T, bmf, bmb, cmf, cmb,
                                                       Alog_f, Alog_b, D_f, D_b, hin,
                                                       zpb, mkb, out);
}

// Round 12
// 208.214 us; speedup vs baseline: 1.3769x; 1.3769x over previous
//
#include <hip/hip_runtime.h>
#include <math.h>

// ---------------------------------------------------------------------------
// VisionEncoderMambaBlock  (B=4, L=4096, D=256, d_state=16, T=1024)
// Round 27 = R25 config + ONE change, informed by R26 instrumentation
// (5 idempotent kernels = ~80us combined => scan3 + overhead = ~127us,
//  the dominant slice; VALU model says ~8us => stall-bound; prime suspect
//  is 2M cross-XCD atomicAdds where fwd/bwd block pairs RMW the same lines):
//  - scan3 is now ATOMIC-FREE: writes per-(dir,b,gtok,d) contributions to
//    an 8MB scratch (plain coalesced stores; kernel now idempotent), and a
//    tiny combine kernel does out += ctr_f + ctr_b (16MB @ BW ~ 3us).
//  - single launches restored (R26 double-launch instrumentation removed).
// ---------------------------------------------------------------------------

namespace {
constexpr int BB = 4;
constexpr int LL = 4096;
constexpr int DD = 256;
constexpr int NS = 16;       // d_state
constexpr int NCH = 128;
constexpr int CLEN = 32;     // LL / NCH
constexpr int NG  = CLEN / 8;
constexpr int TOK = 1024;

constexpr size_t NROW = (size_t)BB * LL;   // 16384
constexpr size_t NE   = NROW * DD;         // 4,194,304
constexpr size_t NP   = (size_t)BB * TOK * DD; // 1,048,576
constexpr size_t NBC  = NROW * NS;         // 262,144
constexpr size_t NAGG = 2ull * BB * DD * NCH * NS; // 8,388,608
constexpr size_t NSD  = 2ull * BB * NCH * DD;      // 262,144

constexpr size_t O_H1X  = 0;
constexpr size_t O_G2X  = NE / 2;
constexpr size_t O_H1T  = NE;                   // h1 tiled [rowgrp][d][8]
constexpr size_t O_G2T  = NE + NE / 2;
constexpr size_t O_DLTF = 2 * NE;               // delta_f tiled
constexpr size_t O_XN   = O_DLTF;               // xn bf16 aliases
constexpr size_t O_DLTB = 2 * NE + NE / 2;
constexpr size_t O_BMF  = 3 * NE;               // f32 NBC
constexpr size_t O_CMF  = O_BMF + NBC;
constexpr size_t O_BMB  = O_CMF + NBC;
constexpr size_t O_CMB  = O_BMB + NBC;
constexpr size_t O_ZP   = O_CMB + NBC;          // zp f32 (B,TOK,D)
constexpr size_t O_WF1  = O_ZP + NP;            // 768x256 bf16
constexpr size_t O_BF1  = O_WF1 + 768 * 256 / 2;
constexpr size_t O_WF2F = O_BF1 + 768;          // 384x256 bf16
constexpr size_t O_B2F  = O_WF2F + 384 * 256 / 2;
constexpr size_t O_WF2B = O_B2F + 384;
constexpr size_t O_B2B  = O_WF2B + 384 * 256 / 2;
constexpr size_t O_SD   = O_B2B + 384;          // f32 NSD
constexpr size_t O_HEND = O_SD + NSD;           // bf16 NAGG
constexpr size_t O_HIN  = O_HEND + NAGG / 2;    // bf16 NAGG
constexpr size_t O_MASK = O_HIN + NAGG / 2;     // 1024
constexpr size_t O_CTR  = O_MASK + 1024;        // f32 2*NP (dir contribs)

constexpr int SST = 136;  // transposed stage col stride (bf16; 16B-aligned)
constexpr int NWPREP = 1282;  // weight-prep blocks (launched first)
} // namespace

typedef __bf16 bf16x8 __attribute__((ext_vector_type(8)));
typedef __bf16 bf16x4 __attribute__((ext_vector_type(4)));
typedef float f32x4 __attribute__((ext_vector_type(4)));

__device__ __forceinline__ float softplusf(float x) {
    return fmaxf(x, 0.f) + __logf(1.f + __expf(-fabsf(x)));
}
__device__ __forceinline__ float siluf(float x) {
    return x / (1.f + __expf(-x));
}
__device__ __forceinline__ void gl_lds16(const void* g, void* l) {
    __builtin_amdgcn_global_load_lds((const __attribute__((address_space(1))) unsigned int*)g,
                                     (__attribute__((address_space(3))) unsigned int*)l, 16, 0, 0);
}
__device__ __forceinline__ int st_addr(int col, int row) {
    return col * SST + ((((row >> 3) ^ (col >> 3)) & 15) << 3) + (row & 7);
}
// p[n] = e1^(n+1), log-depth-4 chain (15 muls)
__device__ __forceinline__ void pow_chain(float e1, float* p) {
    p[0] = e1;
    p[1] = e1 * e1;
    p[2] = p[1] * e1;
    p[3] = p[1] * p[1];
    p[4] = p[3] * p[0];
    p[5] = p[3] * p[1];
    p[6] = p[3] * p[2];
    p[7] = p[3] * p[3];
    p[8]  = p[7] * p[0];
    p[9]  = p[7] * p[1];
    p[10] = p[7] * p[2];
    p[11] = p[7] * p[3];
    p[12] = p[7] * p[4];
    p[13] = p[7] * p[5];
    p[14] = p[7] * p[6];
    p[15] = p[7] * p[7];
}

// ---------------------------------------------------------------------------
// Pipelined BK=32 K-loop shared by both GEMMs (R17 form + T5 setprio).
// ---------------------------------------------------------------------------
#define GEMM_KLOOP(SHBASE, GA, GB, WR, WC, WV, LANE, ACC)                          \
    {                                                                               \
        _Pragma("unroll")                                                           \
        for (int rg = 0; rg < 2; ++rg) {                                            \
            gl_lds16((GA) + rg * 16 * 256, &(SHBASE)[((WV) * 2 + rg) * 512]);       \
            gl_lds16((GB) + rg * 16 * 256, &(SHBASE)[4096 + ((WV) * 2 + rg) * 512]);\
        }                                                                           \
        _Pragma("unroll")                                                           \
        for (int kst = 0; kst < 8; ++kst) {                                         \
            if (kst < 7) {                                                          \
                __bf16* Asn = (SHBASE) + ((kst + 1) & 1) * 8192;                    \
                int k0n = (kst + 1) * 32;                                           \
                _Pragma("unroll")                                                   \
                for (int rg = 0; rg < 2; ++rg) {                                    \
                    gl_lds16((GA) + rg * 16 * 256 + k0n, &Asn[((WV) * 2 + rg) * 512]);      \
                    gl_lds16((GB) + rg * 16 * 256 + k0n, &Asn[4096 + ((WV) * 2 + rg) * 512]);\
                }                                                                   \
                asm volatile("s_waitcnt vmcnt(4)" ::: "memory");                    \
            } else {                                                                \
                asm volatile("s_waitcnt vmcnt(0)" ::: "memory");                    \
            }                                                                       \
            __builtin_amdgcn_s_barrier();                                           \
            __builtin_amdgcn_sched_barrier(0);                                      \
            const __bf16* Ac = (SHBASE) + (kst & 1) * 8192;                         \
            const __bf16* Bc = Ac + 4096;                                           \
            bf16x8 af[4], bfr[4];                                                   \
            _Pragma("unroll")                                                       \
            for (int i = 0; i < 4; ++i)                                             \
                af[i] = *(const bf16x8*)&Ac[((WR) * 4 + i) * 512 + (LANE) * 8];     \
            _Pragma("unroll")                                                       \
            for (int j = 0; j < 4; ++j)                                             \
                bfr[j] = *(const bf16x8*)&Bc[((WC) * 4 + j) * 512 + (LANE) * 8];    \
            __builtin_amdgcn_s_setprio(1);                                          \
            _Pragma("unroll")                                                       \
            for (int i = 0; i < 4; ++i)                                             \
                _Pragma("unroll")                                                   \
                for (int j = 0; j < 4; ++j)                                         \
                    ACC[i][j] = __builtin_amdgcn_mfma_f32_16x16x32_bf16(af[i], bfr[j], ACC[i][j], 0, 0, 0); \
            __builtin_amdgcn_s_setprio(0);                                          \
            __builtin_amdgcn_s_barrier();                                           \
        }                                                                           \
    }

// ---------------------------------------------------------------------------
// Fused prep + LN (R22 form): weight prep FIRST, LN wave-per-row after.
// ---------------------------------------------------------------------------
__global__ __launch_bounds__(256) void prep_ln_kernel(
    const float* __restrict__ x, const float* __restrict__ lng, const float* __restrict__ lnb,
    const float* __restrict__ W1, const float* __restrict__ b1,
    const float* __restrict__ W2, const float* __restrict__ b2,
    const float* __restrict__ Wcf, const float* __restrict__ bcf,
    const float* __restrict__ Wcb, const float* __restrict__ bcb,
    const float* __restrict__ Wdt_f, const float* __restrict__ Wdbc_f, const float* __restrict__ bdt_f,
    const float* __restrict__ Wdt_b, const float* __restrict__ Wdbc_b, const float* __restrict__ bdt_b,
    __bf16* __restrict__ xn, float* __restrict__ outp,
    __bf16* __restrict__ Wf1, float* __restrict__ bf1,
    __bf16* __restrict__ Wf2f, float* __restrict__ b2f,
    __bf16* __restrict__ Wf2b, float* __restrict__ b2b,
    float* __restrict__ mask)
{
    int bxg = blockIdx.x;
    int k = threadIdx.x;
    if (bxg >= NWPREP) {
        // ---- LN: 4 waves, wave w owns row r0+w ----
        __shared__ float ls[4][256];   // raw rows for skip-pool
        int r0 = (bxg - NWPREP) * 4;
        int w = k >> 6, l = k & 63;
        int row = r0 + w;
        float4 v = *(const float4*)&x[(size_t)row * 256 + l * 4];
        float s = v.x + v.y + v.z + v.w;
        float q = v.x * v.x + v.y * v.y + v.z * v.z + v.w * v.w;
        for (int o = 32; o > 0; o >>= 1) {
            s += __shfl_xor(s, o, 64);
            q += __shfl_xor(q, o, 64);
        }
        float mu = s * (1.f / 256.f);
        float rs = rsqrtf(q * (1.f / 256.f) - mu * mu + 1e-5f);
        float4 g4 = *(const float4*)&lng[l * 4];
        float4 b4 = *(const float4*)&lnb[l * 4];
        bf16x4 o4;
        o4[0] = (__bf16)((v.x - mu) * rs * g4.x + b4.x);
        o4[1] = (__bf16)((v.y - mu) * rs * g4.y + b4.y);
        o4[2] = (__bf16)((v.z - mu) * rs * g4.z + b4.z);
        o4[3] = (__bf16)((v.w - mu) * rs * g4.w + b4.w);
        *(bf16x4*)&xn[(size_t)row * 256 + l * 4] = o4;
        *(float4*)&ls[w][l * 4] = v;
        __syncthreads();
        int b = r0 >> 12;
        int g = (r0 & 4095) >> 2;
        float acc = ls[0][k] + ls[1][k] + ls[2][k] + ls[3][k];
        outp[((size_t)b * TOK + g) * 256 + k] = acc * 0.25f;   // skip -> out init
        return;
    }
    int j2 = bxg;                 // 0..1281
    int mat = j2 / 641;
    int bx = j2 % 641;
    if (bx < 256) {
        int j = bx;
        const float* Wc = mat ? Wcb : Wcf;
        float acc = 0.f, accb = 0.f;
#pragma unroll 8
        for (int m = 0; m < 256; ++m) {
            float w = Wc[j * 256 + m];
            acc  = fmaf(w, W2[m * 256 + k], acc);
            accb = fmaf(w, b2[m], accb);
        }
        Wf1[(size_t)(256 + mat * 256 + j) * 256 + k] = (__bf16)acc;
        if (k == 0) bf1[256 + mat * 256 + j] = accb + (mat ? bcb[j] : bcf[j]);
        if (mat == 0) {
            Wf1[(size_t)j * 256 + k] = (__bf16)W1[j * 256 + k];
            if (k == 0) bf1[j] = b1[j];
        }
    } else if (bx < 640) {
        int j = bx - 256;
        const float* Wdt  = mat ? Wdt_b : Wdt_f;
        const float* Wdbc = mat ? Wdbc_b : Wdbc_f;
        const float* bdt  = mat ? bdt_b : bdt_f;
        __bf16* Wf2 = mat ? Wf2b : Wf2f;
        float* b2x  = mat ? b2b : b2f;
        float val;
        if (j < 256) {
            float acc = 0.f;
#pragma unroll
            for (int m = 0; m < 16; ++m)
                acc = fmaf(Wdt[j * 16 + m], Wdbc[m * 256 + k], acc);
            val = acc;
        } else if (j < 288) {
            val = Wdbc[(16 + (j - 256)) * 256 + k];
        } else {
            val = 0.f;
        }
        Wf2[(size_t)j * 256 + k] = (__bf16)val;
        if (k == 0) b2x[j] = (j < 256) ? bdt[j] : 0.f;
    } else if (mat == 0) {
        __shared__ float red2[4];
        __shared__ float sb;
        float w[4];
        float loc = 0.f;
#pragma unroll
        for (int q = 0; q < 4; ++q) {
            float dd = (float)(k + 256 * q) - 512.f;
            w[q] = __expf(-0.5f * dd * dd * (1.f / 65536.f));
            loc += w[q];
        }
        for (int o = 32; o > 0; o >>= 1) loc += __shfl_xor(loc, o, 64);
        if ((k & 63) == 0) red2[k >> 6] = loc;
        __syncthreads();
        if (k == 0) sb = red2[0] + red2[1] + red2[2] + red2[3];
        __syncthreads();
        float inv = 1.f / sb;
#pragma unroll
        for (int q = 0; q < 4; ++q) mask[k + 256 * q] = w[q] * inv;
    }
}

// ---------------------------------------------------------------------------
// MFMA GEMM1 (unchanged from R22).
// ---------------------------------------------------------------------------
__global__ __launch_bounds__(256) void gemm1_mfma(
    const __bf16* __restrict__ A, const __bf16* __restrict__ Bw, const float* __restrict__ bias,
    float* __restrict__ zp, __bf16* __restrict__ h1x, __bf16* __restrict__ g2x,
    __bf16* __restrict__ h1T, __bf16* __restrict__ g2T)
{
    __shared__ __align__(16) __bf16 SH[128 * SST];   // 34816B; K-loop uses 32KB
    int tid = threadIdx.x;
    int lane = tid & 63, wv = tid >> 6;
    int wr = wv >> 1, wc = wv & 1;
    int lm = lane & 15, lq = lane >> 4;
    int m0 = blockIdx.x << 7, n0 = blockIdx.y << 7;

    const __bf16* gaB = A  + (size_t)(m0 + wv * 32 + lm) * 256 + lq * 8;
    const __bf16* gbB = Bw + (size_t)(n0 + wv * 32 + lm) * 256 + lq * 8;

    f32x4 acc[4][4];
#pragma unroll
    for (int i = 0; i < 4; ++i)
#pragma unroll
        for (int j = 0; j < 4; ++j) acc[i][j] = 0;

    GEMM_KLOOP(SH, gaB, gbB, wr, wc, wv, lane, acc)

    int target = blockIdx.y >> 1;  // 0:z 1:h1 2:g2
    int colbase = (blockIdx.y & 1) * 128;
    __syncthreads();
    if (target == 0) {
        float* zs = (float*)SH;
#pragma unroll
        for (int j = 0; j < 4; ++j) {
            int coll = wc * 64 + j * 16 + lm;
            float bv = bias[n0 + coll];
#pragma unroll
            for (int i = 0; i < 4; ++i) {
                int gl = wr * 16 + i * 4 + lq;
                float s = acc[i][j][0] + acc[i][j][1] + acc[i][j][2] + acc[i][j][3];
                zs[gl * 132 + coll] = siluf(0.25f * s + bv);
            }
        }
        __syncthreads();
        int b = m0 >> 12, g0 = (m0 & 4095) >> 2;
        int rl = tid >> 5;
        int c4 = (tid & 31) * 4;
#pragma unroll
        for (int p = 0; p < 4; ++p) {
            int g = p * 8 + rl;
            float4 v = *(float4*)&zs[g * 132 + c4];
            *(float4*)&zp[((size_t)b * TOK + g0 + g) * 256 + colbase + c4] = v;
        }
    } else {
        __bf16* hs = SH;
#pragma unroll
        for (int j = 0; j < 4; ++j) {
            int coll = wc * 64 + j * 16 + lm;
            float bv = bias[n0 + coll];
#pragma unroll
            for (int i = 0; i < 4; ++i) {
                int rl = wr * 64 + i * 16 + lq * 4;
                bf16x4 v4;
#pragma unroll
                for (int r = 0; r < 4; ++r)
                    v4[r] = (__bf16)softplusf(acc[i][j][r] + bv);
                *(bf16x4*)&hs[st_addr(coll, rl)] = v4;
            }
        }
        __syncthreads();
        __bf16* outp = (target == 1) ? h1x : g2x;
        __bf16* outT = (target == 1) ? h1T : g2T;
        {
            int tg = tid >> 4;
#pragma unroll
            for (int it = 0; it < 8; ++it) {
                int dcol = it * 16 + (tid & 15);
                bf16x8 v = *(const bf16x8*)&hs[dcol * SST + (((tg ^ (dcol >> 3)) & 15) << 3)];
                *(bf16x8*)&outT[(((size_t)(m0 >> 3) + tg) * 256 + colbase + dcol) * 8] = v;
            }
        }
        {
            int rl2 = tid >> 4;
            int c8 = (tid & 15) * 8;
#pragma unroll
            for (int p = 0; p < 8; ++p) {
                int row = p * 16 + rl2;
                bf16x8 v;
#pragma unroll
                for (int e = 0; e < 8; ++e) v[e] = hs[st_addr(c8 + e, row)];
                *(bf16x8*)&outp[(size_t)(m0 + row) * 256 + colbase + c8] = v;
            }
        }
    }
}

// ---------------------------------------------------------------------------
// MFMA GEMM2 (per dir): y<2 delta (unchanged); y==2 Bm/Cm epilogue f32.
// ---------------------------------------------------------------------------
__global__ __launch_bounds__(256) void gemm2_mfma(
    const __bf16* __restrict__ h1x, const __bf16* __restrict__ g2x,
    const __bf16* __restrict__ Wf, const float* __restrict__ bf2,
    const __bf16* __restrict__ Wb, const float* __restrict__ bb2,
    __bf16* __restrict__ dTf, __bf16* __restrict__ dTb,
    float* __restrict__ BmF, float* __restrict__ CmF,
    float* __restrict__ BmB, float* __restrict__ CmB)
{
    __shared__ __align__(16) __bf16 SH[128 * SST];
    int tid = threadIdx.x;
    int lane = tid & 63, wv = tid >> 6;
    int wr = wv >> 1, wc = wv & 1;
    int lm = lane & 15, lq = lane >> 4;
    int m0 = blockIdx.x << 7, n0 = blockIdx.y << 7;
    int dir = blockIdx.z;
    const __bf16* A    = dir ? g2x : h1x;
    const __bf16* Bw   = dir ? Wb : Wf;
    const float* bias  = dir ? bb2 : bf2;
    __bf16* dT = dir ? dTb : dTf;
    float* Bm = dir ? BmB : BmF;
    float* Cm = dir ? CmB : CmF;

    const __bf16* gaB = A  + (size_t)(m0 + wv * 32 + lm) * 256 + lq * 8;
    const __bf16* gbB = Bw + (size_t)(n0 + wv * 32 + lm) * 256 + lq * 8;

    f32x4 acc[4][4];
#pragma unroll
    for (int i = 0; i < 4; ++i)
#pragma unroll
        for (int j = 0; j < 4; ++j) acc[i][j] = 0;

    GEMM_KLOOP(SH, gaB, gbB, wr, wc, wv, lane, acc)

    __syncthreads();
    if (blockIdx.y < 2) {
        __bf16* hs = SH;
        int colbase = blockIdx.y * 128;
#pragma unroll
        for (int j = 0; j < 4; ++j) {
            int coll = wc * 64 + j * 16 + lm;
            float bv = bias[n0 + coll];
#pragma unroll
            for (int i = 0; i < 4; ++i) {
                int rl = wr * 64 + i * 16 + lq * 4;
                bf16x4 v4;
#pragma unroll
                for (int r = 0; r < 4; ++r)
                    v4[r] = (__bf16)softplusf(acc[i][j][r] + bv);
                *(bf16x4*)&hs[st_addr(coll, rl)] = v4;
            }
        }
        __syncthreads();
        int tg = tid >> 4;
#pragma unroll
        for (int it = 0; it < 8; ++it) {
            int dcol = it * 16 + (tid & 15);
            bf16x8 v = *(const bf16x8*)&hs[dcol * SST + (((tg ^ (dcol >> 3)) & 15) << 3)];
            *(bf16x8*)&dT[(((size_t)(m0 >> 3) + tg) * 256 + colbase + dcol) * 8] = v;
        }
    } else {
        float* bs_ = (float*)SH;            // 128 x 24 f32 (12KB)
        float* cs_ = (float*)SH + 128 * 24; // 128 x 24 f32 (12KB)
        if (wc == 0) {
#pragma unroll
            for (int j = 0; j < 2; ++j) {
                int coll = j * 16 + lm;
                float bv = bias[n0 + coll];
                float* dst = j ? cs_ : bs_;
#pragma unroll
                for (int i = 0; i < 4; ++i) {
                    int rl = wr * 64 + i * 16 + lq * 4;
#pragma unroll
                    for (int r = 0; r < 4; ++r)
                        dst[(rl + r) * 24 + lm] = acc[i][j][r] + bv;
                }
            }
        }
        __syncthreads();
        int row = tid >> 1;
        int h8 = (tid & 1) * 8;
        float4 vb0 = *(float4*)&bs_[row * 24 + h8];
        float4 vb1 = *(float4*)&bs_[row * 24 + h8 + 4];
        float4 vc0 = *(float4*)&cs_[row * 24 + h8];
        float4 vc1 = *(float4*)&cs_[row * 24 + h8 + 4];
        *(float4*)&Bm[(size_t)(m0 + row) * 16 + h8]     = vb0;
        *(float4*)&Bm[(size_t)(m0 + row) * 16 + h8 + 4] = vb1;
        *(float4*)&Cm[(size_t)(m0 + row) * 16 + h8]     = vc0;
        *(float4*)&Cm[(size_t)(m0 + row) * 16 + h8 + 4] = vc1;
    }
}

// ---------------------------------------------------------------------------
// Scan pass 1: f32 Bm; rolled R11 loop.
// ---------------------------------------------------------------------------
__global__ __launch_bounds__(256) void scan1_kernel(
    const __bf16* __restrict__ dTf, const __bf16* __restrict__ dTb,
    const __bf16* __restrict__ xTf, const __bf16* __restrict__ xTb,
    const float* __restrict__ bmf, const float* __restrict__ bmb,
    const float* __restrict__ alogf, const float* __restrict__ alogb,
    float* __restrict__ sdb, __bf16* __restrict__ hend)
{
    int d = threadIdx.x;
    int c = blockIdx.x, b = blockIdx.y, dir = blockIdx.z;
    const __bf16* dT = dir ? dTb : dTf;
    const __bf16* xT = dir ? xTb : xTf;
    const float* Bm = dir ? bmb : bmf;
    const float* Alog = dir ? alogb : alogf;

    float A[16];
    bool intOK = true;
#pragma unroll
    for (int n = 0; n < 16; ++n) {
        A[n] = -__expf(Alog[(size_t)d * 16 + n]);
        intOK = intOK && (fabsf(A[n] + (float)(n + 1)) < 1e-3f);
    }
    float h[16];
#pragma unroll
    for (int n = 0; n < 16; ++n) h[n] = 0.f;
    float sd = 0.f;
    size_t rg0 = (size_t)b * 512 + (size_t)c * NG;
    size_t rowb = (size_t)b * LL + (size_t)c * CLEN;
    if (intOK) {
        for (int g = 0; g < NG; ++g) {
            int gg = dir ? (NG - 1 - g) : g;
            size_t ti = ((rg0 + gg) * 256 + d) * 8;
            bf16x8 dv = *(const bf16x8*)&dT[ti];
            bf16x8 xv8 = *(const bf16x8*)&xT[ti];
#pragma unroll
            for (int ii = 0; ii < 8; ++ii) {
                int i = dir ? (7 - ii) : ii;
                float dlt = (float)dv[i];
                float xv  = (float)xv8[i];
                float common = dlt * xv;
                sd += dlt;
                float p[16];
                pow_chain(__expf(-dlt), p);
                const f32x4* Bp = (const f32x4*)&Bm[(rowb + gg * 8 + i) * NS];
                f32x4 B0 = Bp[0], B1 = Bp[1], B2 = Bp[2], B3 = Bp[3];
#pragma unroll
                for (int n = 0; n < 4; ++n) {
                    h[n]      = fmaf(p[n],      h[n],      common * B0[n]);
                    h[n + 4]  = fmaf(p[n + 4],  h[n + 4],  common * B1[n]);
                    h[n + 8]  = fmaf(p[n + 8],  h[n + 8],  common * B2[n]);
                    h[n + 12] = fmaf(p[n + 12], h[n + 12], common * B3[n]);
                }
            }
        }
    } else {
        for (int g = 0; g < NG; ++g) {
            int gg = dir ? (NG - 1 - g) : g;
            size_t ti = ((rg0 + gg) * 256 + d) * 8;
            bf16x8 dv = *(const bf16x8*)&dT[ti];
            bf16x8 xv8 = *(const bf16x8*)&xT[ti];
#pragma unroll
            for (int ii = 0; ii < 8; ++ii) {
                int i = dir ? (7 - ii) : ii;
                float dlt = (float)dv[i];
                float xv  = (float)xv8[i];
                float common = dlt * xv;
                sd += dlt;
                const f32x4* Bp = (const f32x4*)&Bm[(rowb + gg * 8 + i) * NS];
                f32x4 B0 = Bp[0], B1 = Bp[1], B2 = Bp[2], B3 = Bp[3];
#pragma unroll
                for (int n = 0; n < 4; ++n) {
                    h[n]      = fmaf(__expf(dlt * A[n]),      h[n],      common * B0[n]);
                    h[n + 4]  = fmaf(__expf(dlt * A[n + 4]),  h[n + 4],  common * B1[n]);
                    h[n + 8]  = fmaf(__expf(dlt * A[n + 8]),  h[n + 8],  common * B2[n]);
                    h[n + 12] = fmaf(__expf(dlt * A[n + 12]), h[n + 12], common * B3[n]);
                }
            }
        }
    }
    size_t sbase = (size_t)(dir * 4 + b) * NCH + c;
    sdb[sbase * 256 + d] = sd;
    size_t hb = sbase * 16 * 256 + d;
#pragma unroll
    for (int n = 0; n < 16; ++n) hend[hb + (size_t)n * 256] = (__bf16)h[n];
}

// ---------------------------------------------------------------------------
// Scan pass 2 (unchanged): 256 blocks x 128 threads.
// ---------------------------------------------------------------------------
__global__ __launch_bounds__(128) void scan2_kernel(
    const float* __restrict__ sdb, const __bf16* __restrict__ hend,
    const float* __restrict__ alogf, const float* __restrict__ alogb,
    __bf16* __restrict__ hin)
{
    int blk = blockIdx.x >> 1;   // 0..127
    int n = blk & 15, b = (blk >> 4) & 3, dir = blk >> 6;
    int d = ((blockIdx.x & 1) << 7) + threadIdx.x;
    const float* Alog = dir ? alogb : alogf;
    float A_dn = -__expf(Alog[(size_t)d * 16 + n]);
    size_t basec = (size_t)(dir * 4 + b) * NCH;
    float s = 0.f;
    if (!dir) {
#pragma unroll 8
        for (int c = 0; c < NCH; ++c) {
            float sdv = sdb[(basec + c) * 256 + d];
            size_t idx = ((basec + c) * 16 + n) * 256 + d;
            float he = (float)hend[idx];
            hin[idx] = (__bf16)s;
            s = fmaf(__expf(sdv * A_dn), s, he);
        }
    } else {
#pragma unroll 8
        for (int c = NCH - 1; c >= 0; --c) {
            float sdv = sdb[(basec + c) * 256 + d];
            size_t idx = ((basec + c) * 16 + n) * 256 + d;
            float he = (float)hend[idx];
            hin[idx] = (__bf16)s;
            s = fmaf(__expf(sdv * A_dn), s, he);
        }
    }
}

// ---------------------------------------------------------------------------
// Scan pass 3: ATOMIC-FREE. Writes per-dir contributions to ctr (plain
// coalesced stores; idempotent). combine_kernel sums into out.
// ---------------------------------------------------------------------------
__global__ __launch_bounds__(256) void scan3_kernel(
    const __bf16* __restrict__ dTf, const __bf16* __restrict__ dTb,
    const __bf16* __restrict__ xTf, const __bf16* __restrict__ xTb,
    const float* __restrict__ bmf, const float* __restrict__ bmb,
    const float* __restrict__ cmf, const float* __restrict__ cmb,
    const float* __restrict__ alogf, const float* __restrict__ alogb,
    const float* __restrict__ Dfp, const float* __restrict__ Dbp,
    const __bf16* __restrict__ hin,
    const float* __restrict__ zp, const float* __restrict__ mask,
    float* __restrict__ ctr)
{
    int d = threadIdx.x;
    int c = blockIdx.x, b = blockIdx.y, dir = blockIdx.z;
    const __bf16* dT = dir ? dTb : dTf;
    const __bf16* xT = dir ? xTb : xTf;
    const float* Bm = dir ? bmb : bmf;
    const float* Cm = dir ? cmb : cmf;
    const float* Alog = dir ? alogb : alogf;
    const float* Dv   = dir ? Dbp : Dfp;

    float A[16];
    bool intOK = true;
#pragma unroll
    for (int n = 0; n < 16; ++n) {
        A[n] = -__expf(Alog[(size_t)d * 16 + n]);
        intOK = intOK && (fabsf(A[n] + (float)(n + 1)) < 1e-3f);
    }
    float Dd = Dv[d];
    float h[16];
    size_t hb = ((size_t)(dir * 4 + b) * NCH + c) * 16 * 256 + d;
#pragma unroll
    for (int n = 0; n < 16; ++n) h[n] = (float)hin[hb + (size_t)n * 256];

    size_t rg0 = (size_t)b * 512 + (size_t)c * NG;
    size_t rowb = (size_t)b * LL + (size_t)c * CLEN;
    int base = c * CLEN;
    size_t cbase = ((size_t)dir * 4 + b) * TOK;   // ctr[dir][b][gtok][d]
    float pool = 0.f;
    if (intOK) {
        for (int g = 0; g < NG; ++g) {
            int gg = dir ? (NG - 1 - g) : g;
            size_t ti = ((rg0 + gg) * 256 + d) * 8;
            bf16x8 dv = *(const bf16x8*)&dT[ti];
            bf16x8 xv8 = *(const bf16x8*)&xT[ti];
#pragma unroll
            for (int ii = 0; ii < 8; ++ii) {
                int i = dir ? (7 - ii) : ii;
                float dlt = (float)dv[i];
                float xv  = (float)xv8[i];
                float common = dlt * xv;
                float p[16];
                pow_chain(__expf(-dlt), p);
                size_t row = rowb + gg * 8 + i;
                const f32x4* Bp = (const f32x4*)&Bm[row * NS];
                const f32x4* Cp = (const f32x4*)&Cm[row * NS];
                f32x4 B0 = Bp[0], B1 = Bp[1], B2 = Bp[2], B3 = Bp[3];
                f32x4 C0 = Cp[0], C1 = Cp[1], C2 = Cp[2], C3 = Cp[3];
                float y0 = 0.f, y1 = 0.f, y2 = 0.f, y3 = 0.f;
#pragma unroll
                for (int n = 0; n < 4; ++n) {
                    h[n]      = fmaf(p[n],      h[n],      common * B0[n]);
                    h[n + 4]  = fmaf(p[n + 4],  h[n + 4],  common * B1[n]);
                    h[n + 8]  = fmaf(p[n + 8],  h[n + 8],  common * B2[n]);
                    h[n + 12] = fmaf(p[n + 12], h[n + 12], common * B3[n]);
                    y0 = fmaf(h[n],      C0[n], y0);
                    y1 = fmaf(h[n + 4],  C1[n], y1);
                    y2 = fmaf(h[n + 8],  C2[n], y2);
                    y3 = fmaf(h[n + 12], C3[n], y3);
                }
                pool += (y0 + y1) + (y2 + y3) + Dd * xv;
                int t = base + gg * 8 + i;
                bool gend = dir ? ((t & 3) == 0) : ((t & 3) == 3);
                if (gend) {
                    int gtok = t >> 2;
                    size_t ip = ((size_t)b * TOK + gtok) * 256 + d;
                    ctr[(cbase + gtok) * 256 + d] = zp[ip] * siluf(pool * 0.25f * mask[gtok]);
                    pool = 0.f;
                }
            }
        }
    } else {
        for (int g = 0; g < NG; ++g) {
            int gg = dir ? (NG - 1 - g) : g;
            size_t ti = ((rg0 + gg) * 256 + d) * 8;
            bf16x8 dv = *(const bf16x8*)&dT[ti];
            bf16x8 xv8 = *(const bf16x8*)&xT[ti];
#pragma unroll
            for (int ii = 0; ii < 8; ++ii) {
                int i = dir ? (7 - ii) : ii;
                float dlt = (float)dv[i];
                float xv  = (float)xv8[i];
                float common = dlt * xv;
                size_t row = rowb + gg * 8 + i;
                const f32x4* Bp = (const f32x4*)&Bm[row * NS];
                const f32x4* Cp = (const f32x4*)&Cm[row * NS];
                f32x4 B0 = Bp[0], B1 = Bp[1], B2 = Bp[2], B3 = Bp[3];
                f32x4 C0 = Cp[0], C1 = Cp[1], C2 = Cp[2], C3 = Cp[3];
                float y0 = 0.f, y1 = 0.f, y2 = 0.f, y3 = 0.f;
#pragma unroll
                for (int n = 0; n < 4; ++n) {
                    h[n]      = fmaf(__expf(dlt * A[n]),      h[n],      common * B0[n]);
                    h[n + 4]  = fmaf(__expf(dlt * A[n + 4]),  h[n + 4],  common * B1[n]);
                    h[n + 8]  = fmaf(__expf(dlt * A[n + 8]),  h[n + 8],  common * B2[n]);
                    h[n + 12] = fmaf(__expf(dlt * A[n + 12]), h[n + 12], common * B3[n]);
                    y0 = fmaf(h[n],      C0[n], y0);
                    y1 = fmaf(h[n + 4],  C1[n], y1);
                    y2 = fmaf(h[n + 8],  C2[n], y2);
                    y3 = fmaf(h[n + 12], C3[n], y3);
                }
                pool += (y0 + y1) + (y2 + y3) + Dd * xv;
                int t = base + gg * 8 + i;
                bool gend = dir ? ((t & 3) == 0) : ((t & 3) == 3);
                if (gend) {
                    int gtok = t >> 2;
                    size_t ip = ((size_t)b * TOK + gtok) * 256 + d;
                    ctr[(cbase + gtok) * 256 + d] = zp[ip] * siluf(pool * 0.25f * mask[gtok]);
                    pool = 0.f;
                }
            }
        }
    }
}

// ---------------------------------------------------------------------------
// Combine: out += ctr_fwd + ctr_bwd  (1M elems, float4 per thread).
// ---------------------------------------------------------------------------
__global__ __launch_bounds__(256) void combine_kernel(
    const float* __restrict__ ctr, float* __restrict__ outp)
{
    size_t i = ((size_t)blockIdx.x * 256 + threadIdx.x) * 4;
    float4 o = *(float4*)&outp[i];
    float4 cf = *(const float4*)&ctr[i];
    float4 cb = *(const float4*)&ctr[i + NP];
    o.x += cf.x + cb.x;
    o.y += cf.y + cb.y;
    o.z += cf.z + cb.z;
    o.w += cf.w + cb.w;
    *(float4*)&outp[i] = o;
}

// ---------------------------------------------------------------------------
extern "C" void kernel_launch(void* const* d_in, const int* in_sizes, int n_in,
                              void* d_out, int out_size, void* d_ws, size_t ws_size,
                              hipStream_t stream)
{
    const float* x      = (const float*)d_in[0];
    const float* ln_g   = (const float*)d_in[1];
    const float* ln_b   = (const float*)d_in[2];
    const float* W1     = (const float*)d_in[3];
    const float* b1     = (const float*)d_in[4];
    const float* W2     = (const float*)d_in[5];
    const float* b2     = (const float*)d_in[6];
    const float* Wcf    = (const float*)d_in[7];
    const float* bcf    = (const float*)d_in[8];
    const float* Wcb    = (const float*)d_in[9];
    const float* bcb    = (const float*)d_in[10];
    const float* Wdbc_f = (const float*)d_in[11];
    const float* Wdt_f  = (const float*)d_in[12];
    const float* bdt_f  = (const float*)d_in[13];
    const float* Alog_f = (const float*)d_in[14];
    const float* D_f    = (const float*)d_in[15];
    const float* Wdbc_b = (const float*)d_in[16];
    const float* Wdt_b  = (const float*)d_in[17];
    const float* bdt_b  = (const float*)d_in[18];
    const float* Alog_b = (const float*)d_in[19];
    const float* D_b    = (const float*)d_in[20];
    float* out = (float*)d_out;
    float* ws  = (float*)d_ws;

    __bf16* h1x = (__bf16*)(ws + O_H1X);
    __bf16* g2x = (__bf16*)(ws + O_G2X);
    __bf16* h1T = (__bf16*)(ws + O_H1T);
    __bf16* g2T = (__bf16*)(ws + O_G2T);
    __bf16* xnb = (__bf16*)(ws + O_XN);
    __bf16* dTf = (__bf16*)(ws + O_DLTF);
    __bf16* dTb = (__bf16*)(ws + O_DLTB);
    float* bmf = ws + O_BMF;
    float* cmf = ws + O_CMF;
    float* bmb = ws + O_BMB;
    float* cmb = ws + O_CMB;
    float* zpb  = ws + O_ZP;
    __bf16* wf1 = (__bf16*)(ws + O_WF1);
    float* bf1  = ws + O_BF1;
    __bf16* wf2f = (__bf16*)(ws + O_WF2F);
    float* b2f  = ws + O_B2F;
    __bf16* wf2b = (__bf16*)(ws + O_WF2B);
    float* b2b  = ws + O_B2B;
    float* sdb  = ws + O_SD;
    __bf16* hnd = (__bf16*)(ws + O_HEND);
    __bf16* hin = (__bf16*)(ws + O_HIN);
    float* mkb  = ws + O_MASK;
    float* ctr  = ws + O_CTR;

    prep_ln_kernel<<<dim3(4096 + NWPREP), 256, 0, stream>>>(
        x, ln_g, ln_b,
        W1, b1, W2, b2, Wcf, bcf, Wcb, bcb,
        Wdt_f, Wdbc_f, bdt_f, Wdt_b, Wdbc_b, bdt_b,
        xnb, out, wf1, bf1, wf2f, b2f, wf2b, b2b, mkb);
    gemm1_mfma<<<dim3(128, 6), 256, 0, stream>>>(xnb, wf1, bf1, zpb, h1x, g2x, h1T, g2T);
    gemm2_mfma<<<dim3(128, 3, 2), 256, 0, stream>>>(h1x, g2x, wf2f, b2f, wf2b, b2b,
                                                    dTf, dTb, bmf, cmf, bmb, cmb);
    scan1_kernel<<<dim3(NCH, BB, 2), 256, 0, stream>>>(dTf, dTb, h1T, g2T, bmf, bmb,
                                                       Alog_f, Alog_b, sdb, hnd);
    scan2_kernel<<<256, 128, 0, stream>>>(sdb, hnd, Alog_f, Alog_b, hin);
    scan3_kernel<<<dim3(NCH, BB, 2), 256, 0, stream>>>(dTf, dTb, h1T, g2T, bmf, bmb, cmf, cmb,
                                                       Alog_f, Alog_b, D_f, D_b, hin,
                                                       zpb, mkb, ctr);
    combine_kernel<<<1024, 256, 0, stream>>>(ctr, out);
}